// Round 31
// baseline (103.050 us; speedup 1.0000x reference)
//
#include <hip/hip_runtime.h>
#include <hip/hip_bf16.h>

#define TQ_D   1024
#define TQ_KC  16
#define MERGE_K 512          // OpenBLAS KC-panel boundary (proven R9)
#define TQ_TOL  1.0e-4f      // ~50 sigma of 4-term MFMA vs serial-f32 error
#define LCAP    1024         // per-block LDS suspect-list capacity

#define SWZ(row, col) ((col) ^ ((((row) >> 3) & 1) << 3))

typedef __attribute__((ext_vector_type(8))) short bf16x8;
typedef __attribute__((ext_vector_type(4))) float f32x4;

__device__ __forceinline__ unsigned short f2bf(float f) {
    union { __hip_bfloat16 h; unsigned short s; } u;
    u.h = __float2bfloat16(f);
    return u.s;
}
__device__ __forceinline__ float bf2f(unsigned short s) {
    union { unsigned int u; float f; } v;
    v.u = (unsigned int)s << 16;
    return v.f;
}

// ---------------------------------------------------------------------------
// Convert + transpose: PhT[n][k] = bf16(Pi[k][n]). 64x64 LDS tiles.
// ---------------------------------------------------------------------------
__global__ __launch_bounds__(256)
void tq_cvt_transpose(const float* __restrict__ Pi,
                      unsigned short* __restrict__ PhT)
{
    __shared__ unsigned short tile[64][68];
    const int tid = threadIdx.x;
    const int k0 = blockIdx.y * 64;
    const int n0 = blockIdx.x * 64;
#pragma unroll
    for (int q = 0; q < 16; ++q) {
        const int idx = q * 256 + tid;
        const int r = idx >> 6, c = idx & 63;
        tile[r][c] = f2bf(Pi[(size_t)(k0 + r) * TQ_D + n0 + c]);
    }
    __syncthreads();
#pragma unroll
    for (int q = 0; q < 16; ++q) {
        const int idx = q * 256 + tid;
        const int r = idx >> 6, c = idx & 63;
        PhT[(size_t)(n0 + r) * TQ_D + k0 + c] = tile[c][r];
    }
}

// ---------------------------------------------------------------------------
// K1-MFMA (4-term, 8-wave, 128x64 — R30 champion + setprio around MFMA).
// ---------------------------------------------------------------------------
__global__ __launch_bounds__(512)
void tq_rq_mfma(const float* __restrict__ X,
                const float* __restrict__ Pi,
                const float* __restrict__ Cent,
                float* __restrict__ OutIdx,
                unsigned* __restrict__ Counter,
                unsigned* __restrict__ List,
                unsigned cap)
{
    __shared__ unsigned short XhS[128][40];
    __shared__ unsigned short XlS[128][40];
    __shared__ unsigned short PhS[64][40];
    __shared__ unsigned short PlS[64][40];
    __shared__ unsigned lcount;
    __shared__ unsigned gbase;
    __shared__ unsigned llist[LCAP];

    const int tid  = threadIdx.x;
    const int lane = tid & 63;
    const int wv   = tid >> 6;
    const int m0 = blockIdx.y * 128;
    const int n0 = blockIdx.x * 64;
    const int wr = (wv >> 1) * 32;
    const int wc = (wv & 1) * 32;
    const int l15 = lane & 15;
    const int k8  = (lane >> 4) * 8;

    const int srow = tid >> 2;
    const int scol = (tid & 3) * 8;
    const int ssc  = SWZ(srow, scol);
    const int brow = tid >> 3;
    const int bcol = (tid & 7) * 4;
    const int bsc  = SWZ(brow, bcol);

    const float* aP = X  + (size_t)(m0 + srow) * TQ_D + scol;
    const float* bP = Pi + (size_t)(n0 + brow) * TQ_D + bcol;

    if (tid == 0) lcount = 0;

    f32x4 acc[2][2];
#pragma unroll
    for (int i = 0; i < 2; ++i)
#pragma unroll
        for (int j = 0; j < 2; ++j)
#pragma unroll
            for (int r = 0; r < 4; ++r) acc[i][j][r] = 0.0f;

    float4 va[2], vb;
#pragma unroll
    for (int q = 0; q < 2; ++q) va[q] = *(const float4*)(aP + 4 * q);
    vb = *(const float4*)(bP);

#pragma unroll
    for (int q = 0; q < 2; ++q) {
        ushort4 ah, al;
        const float* fa = (const float*)&va[q];
        ah.x = f2bf(fa[0]); al.x = f2bf(fa[0] - bf2f(ah.x));
        ah.y = f2bf(fa[1]); al.y = f2bf(fa[1] - bf2f(ah.y));
        ah.z = f2bf(fa[2]); al.z = f2bf(fa[2] - bf2f(ah.z));
        ah.w = f2bf(fa[3]); al.w = f2bf(fa[3] - bf2f(ah.w));
        *(ushort4*)&XhS[srow][ssc + 4 * q] = ah;
        *(ushort4*)&XlS[srow][ssc + 4 * q] = al;
    }
    {
        ushort4 bh, bl;
        const float* fb = (const float*)&vb;
        bh.x = f2bf(fb[0]); bl.x = f2bf(fb[0] - bf2f(bh.x));
        bh.y = f2bf(fb[1]); bl.y = f2bf(fb[1] - bf2f(bh.y));
        bh.z = f2bf(fb[2]); bl.z = f2bf(fb[2] - bf2f(bh.z));
        bh.w = f2bf(fb[3]); bl.w = f2bf(fb[3] - bf2f(bh.w));
        *(ushort4*)&PhS[brow][bsc] = bh;
        *(ushort4*)&PlS[brow][bsc] = bl;
    }
    __syncthreads();

    for (int kt = 0; kt < 32; ++kt) {
        const bool more = (kt + 1) < 32;
        if (more) {
            const float* ap = aP + (kt + 1) * 32;
            const float* bp = bP + (kt + 1) * 32;
#pragma unroll
            for (int q = 0; q < 2; ++q) va[q] = *(const float4*)(ap + 4 * q);
            vb = *(const float4*)(bp);
        }

        bf16x8 afh[2], afl[2], bfh[2], bfl[2];
#pragma unroll
        for (int i = 0; i < 2; ++i) {
            const int r = wr + i * 16 + l15;
            const int kk = SWZ(r, k8);
            afh[i] = *(const bf16x8*)&XhS[r][kk];
            afl[i] = *(const bf16x8*)&XlS[r][kk];
        }
#pragma unroll
        for (int j = 0; j < 2; ++j) {
            const int r = wc + j * 16 + l15;
            const int kk = SWZ(r, k8);
            bfh[j] = *(const bf16x8*)&PhS[r][kk];
            bfl[j] = *(const bf16x8*)&PlS[r][kk];
        }

        __builtin_amdgcn_s_setprio(1);
#pragma unroll
        for (int i = 0; i < 2; ++i)
#pragma unroll
            for (int j = 0; j < 2; ++j) {
                acc[i][j] = __builtin_amdgcn_mfma_f32_16x16x32_bf16(
                    afh[i], bfh[j], acc[i][j], 0, 0, 0);
                acc[i][j] = __builtin_amdgcn_mfma_f32_16x16x32_bf16(
                    afl[i], bfh[j], acc[i][j], 0, 0, 0);
                acc[i][j] = __builtin_amdgcn_mfma_f32_16x16x32_bf16(
                    afh[i], bfl[j], acc[i][j], 0, 0, 0);
                acc[i][j] = __builtin_amdgcn_mfma_f32_16x16x32_bf16(
                    afl[i], bfl[j], acc[i][j], 0, 0, 0);
            }
        __builtin_amdgcn_s_setprio(0);

        if (more) {
            __syncthreads();
#pragma unroll
            for (int q = 0; q < 2; ++q) {
                ushort4 ah, al;
                const float* fa = (const float*)&va[q];
                ah.x = f2bf(fa[0]); al.x = f2bf(fa[0] - bf2f(ah.x));
                ah.y = f2bf(fa[1]); al.y = f2bf(fa[1] - bf2f(ah.y));
                ah.z = f2bf(fa[2]); al.z = f2bf(fa[2] - bf2f(ah.z));
                ah.w = f2bf(fa[3]); al.w = f2bf(fa[3] - bf2f(ah.w));
                *(ushort4*)&XhS[srow][ssc + 4 * q] = ah;
                *(ushort4*)&XlS[srow][ssc + 4 * q] = al;
            }
            {
                ushort4 bh, bl;
                const float* fb = (const float*)&vb;
                bh.x = f2bf(fb[0]); bl.x = f2bf(fb[0] - bf2f(bh.x));
                bh.y = f2bf(fb[1]); bl.y = f2bf(fb[1] - bf2f(bh.y));
                bh.z = f2bf(fb[2]); bl.z = f2bf(fb[2] - bf2f(bh.z));
                bh.w = f2bf(fb[3]); bl.w = f2bf(fb[3] - bf2f(bh.w));
                *(ushort4*)&PhS[brow][bsc] = bh;
                *(ushort4*)&PlS[brow][bsc] = bl;
            }
            __syncthreads();
        }
    }

    float c[TQ_KC];
#pragma unroll
    for (int q = 0; q < TQ_KC; ++q) c[q] = Cent[q];

#pragma unroll
    for (int i = 0; i < 2; ++i)
#pragma unroll
        for (int j = 0; j < 2; ++j)
#pragma unroll
            for (int r = 0; r < 4; ++r) {
                const int row = m0 + wr + i * 16 + (lane >> 4) * 4 + r;
                const int col = n0 + wc + j * 16 + l15;
                const float y = acc[i][j][r];
                int best = 0;
                float bd = fabsf(y - c[0]);
#pragma unroll
                for (int q = 1; q < TQ_KC; ++q) {
                    const float d = fabsf(y - c[q]);
                    if (d < bd) { bd = d; best = q; }
                }
                float dist = 1e30f;
#pragma unroll
                for (int q = 0; q < TQ_KC - 1; ++q) {
                    const float mid = 0.5f * (c[q] + c[q + 1]);
                    dist = fminf(dist, fabsf(y - mid));
                }
                if (dist < TQ_TOL) {
                    const unsigned id = ((unsigned)row << 10) | (unsigned)col;
                    const unsigned ls = atomicAdd(&lcount, 1u);
                    if (ls < LCAP) {
                        llist[ls] = id;
                    } else {
                        const unsigned gs = atomicAdd(Counter, 1u);
                        if (gs < cap) List[gs] = id;
                    }
                }
                OutIdx[(size_t)row * TQ_D + col] = (float)best;
            }

    __syncthreads();
    if (tid == 0) {
        const unsigned cnt = min(lcount, (unsigned)LCAP);
        gbase = (cnt > 0) ? atomicAdd(Counter, cnt) : 0u;
    }
    __syncthreads();
    const unsigned cnt = min(lcount, (unsigned)LCAP);
    for (unsigned s = tid; s < cnt; s += 512) {
        const unsigned g = gbase + s;
        if (g < cap) List[g] = llist[s];
    }
}

// ---------------------------------------------------------------------------
// Fixup (proven R21-R30): 8 suspects/block; exact R9 serial chains from LDS.
// ---------------------------------------------------------------------------
__global__ __launch_bounds__(256)
void tq_fixup_lds(const float* __restrict__ X,
                  const float* __restrict__ Pi,
                  const float* __restrict__ Cent,
                  float* __restrict__ OutIdx,
                  const unsigned* __restrict__ Counter,
                  const unsigned* __restrict__ List,
                  unsigned cap)
{
    __shared__ float Rows[8][2][1024];
    __shared__ float part[8][2];
    __shared__ unsigned ids[8];

    const int tid = threadIdx.x;
    const unsigned count = min(*Counter, cap);

    for (unsigned base = blockIdx.x * 8; base < count; base += gridDim.x * 8) {
        const unsigned nsus = min(8u, count - base);

        if (tid < 8) ids[tid] = (tid < nsus) ? List[base + tid] : 0u;
        __syncthreads();

#pragma unroll
        for (int q = 0; q < 16; ++q) {
            const int lin = q * 256 + tid;
            const int sus = lin >> 9;
            const int rowsel = (lin >> 8) & 1;
            const int f4 = lin & 255;
            if ((unsigned)sus < nsus) {
                const unsigned id = ids[sus];
                const int m = id >> 10;
                const int n = id & (TQ_D - 1);
                const float* src = rowsel ? (Pi + (size_t)n * TQ_D)
                                          : (X + (size_t)m * TQ_D);
                *(float4*)&Rows[sus][rowsel][f4 * 4] =
                    *(const float4*)(src + f4 * 4);
            }
        }
        __syncthreads();

        if (tid < 16 && (unsigned)(tid >> 1) < nsus) {
            const int sus = tid >> 1;
            const int p = tid & 1;
            const int kb = p * MERGE_K;
            float a = 0.0f;
            for (int k = 0; k < MERGE_K; k += 4) {
                const float4 xa = *(const float4*)&Rows[sus][0][kb + k];
                const float4 pa = *(const float4*)&Rows[sus][1][kb + k];
                a = fmaf(xa.x, pa.x, a);
                a = fmaf(xa.y, pa.y, a);
                a = fmaf(xa.z, pa.z, a);
                a = fmaf(xa.w, pa.w, a);
            }
            part[sus][p] = a;
        }
        __syncthreads();

        if (tid < (int)nsus) {
            const float y = part[tid][0] + part[tid][1];
            float c[TQ_KC];
#pragma unroll
            for (int q = 0; q < TQ_KC; ++q) c[q] = Cent[q];
            int best = 0;
            float bd = fabsf(y - c[0]);
#pragma unroll
            for (int q = 1; q < TQ_KC; ++q) {
                const float d = fabsf(y - c[q]);
                if (d < bd) { bd = d; best = q; }
            }
            const unsigned id = ids[tid];
            OutIdx[(size_t)(id >> 10) * TQ_D + (id & (TQ_D - 1))] = (float)best;
        }
        __syncthreads();
    }
}

// ---------------------------------------------------------------------------
// K2-MFMA (8-wave 128x64, PhT input — R30 champion + setprio).
// ---------------------------------------------------------------------------
__global__ __launch_bounds__(512)
void tq_dq_mfma_t(const float* __restrict__ IdxF,
                  const unsigned short* __restrict__ PhT,
                  const float* __restrict__ Cent,
                  float* __restrict__ Xhat)
{
    __shared__ unsigned short Ys[128][40];
    __shared__ unsigned short Ps[64][40];
    __shared__ unsigned short csb[TQ_KC];

    const int tid  = threadIdx.x;
    const int lane = tid & 63;
    const int wv   = tid >> 6;
    const int m0 = blockIdx.y * 128;
    const int n0 = blockIdx.x * 64;
    const int wr = (wv >> 1) * 32;
    const int wc = (wv & 1) * 32;
    const int l15 = lane & 15;
    const int k8  = (lane >> 4) * 8;

    const int srow = tid >> 2;
    const int scol = (tid & 3) * 8;
    const int ssc  = SWZ(srow, scol);
    const int brow = tid >> 3;
    const int bcol = (tid & 7) * 4;
    const int bsc  = SWZ(brow, bcol);

    const float* aP = IdxF + (size_t)(m0 + srow) * TQ_D + scol;
    const unsigned short* bP = PhT + (size_t)(n0 + brow) * TQ_D + bcol;

    if (tid < TQ_KC) csb[tid] = f2bf(Cent[tid]);

    f32x4 acc[2][2];
#pragma unroll
    for (int i = 0; i < 2; ++i)
#pragma unroll
        for (int j = 0; j < 2; ++j)
#pragma unroll
            for (int r = 0; r < 4; ++r) acc[i][j][r] = 0.0f;

    float4 va[2];
    ushort4 vb;
#pragma unroll
    for (int q = 0; q < 2; ++q) va[q] = *(const float4*)(aP + 4 * q);
    vb = *(const ushort4*)(bP);

    __syncthreads();   // csb ready

#pragma unroll
    for (int q = 0; q < 2; ++q) {
        ushort4 w;
        const float* fa = (const float*)&va[q];
        w.x = csb[(int)fa[0] & 15];
        w.y = csb[(int)fa[1] & 15];
        w.z = csb[(int)fa[2] & 15];
        w.w = csb[(int)fa[3] & 15];
        *(ushort4*)&Ys[srow][ssc + 4 * q] = w;
    }
    *(ushort4*)&Ps[brow][bsc] = vb;
    __syncthreads();

    for (int kt = 0; kt < 32; ++kt) {
        const bool more = (kt + 1) < 32;
        if (more) {
            const float* ap = aP + (kt + 1) * 32;
#pragma unroll
            for (int q = 0; q < 2; ++q) va[q] = *(const float4*)(ap + 4 * q);
            vb = *(const ushort4*)(bP + (kt + 1) * 32);
        }

        bf16x8 af[2], bfr[2];
#pragma unroll
        for (int i = 0; i < 2; ++i) {
            const int r = wr + i * 16 + l15;
            af[i] = *(const bf16x8*)&Ys[r][SWZ(r, k8)];
        }
#pragma unroll
        for (int j = 0; j < 2; ++j) {
            const int r = wc + j * 16 + l15;
            bfr[j] = *(const bf16x8*)&Ps[r][SWZ(r, k8)];
        }

        __builtin_amdgcn_s_setprio(1);
#pragma unroll
        for (int i = 0; i < 2; ++i)
#pragma unroll
            for (int j = 0; j < 2; ++j)
                acc[i][j] = __builtin_amdgcn_mfma_f32_16x16x32_bf16(
                    af[i], bfr[j], acc[i][j], 0, 0, 0);
        __builtin_amdgcn_s_setprio(0);

        if (more) {
            __syncthreads();
#pragma unroll
            for (int q = 0; q < 2; ++q) {
                ushort4 w;
                const float* fa = (const float*)&va[q];
                w.x = csb[(int)fa[0] & 15];
                w.y = csb[(int)fa[1] & 15];
                w.z = csb[(int)fa[2] & 15];
                w.w = csb[(int)fa[3] & 15];
                *(ushort4*)&Ys[srow][ssc + 4 * q] = w;
            }
            *(ushort4*)&Ps[brow][bsc] = vb;
            __syncthreads();
        }
    }

#pragma unroll
    for (int i = 0; i < 2; ++i)
#pragma unroll
        for (int j = 0; j < 2; ++j)
#pragma unroll
            for (int r = 0; r < 4; ++r) {
                const int row = wr + i * 16 + (lane >> 4) * 4 + r;
                const int col = wc + j * 16 + l15;
                Xhat[(size_t)(m0 + row) * TQ_D + n0 + col] = acc[i][j][r];
            }
}

// ---------------------------------------------------------------------------
// Fallback K2 (proven R29 fused): transposed scalar staging.
// ---------------------------------------------------------------------------
__global__ __launch_bounds__(512)
void tq_dq_mfma(const float* __restrict__ IdxF,
                const float* __restrict__ Pi,
                const float* __restrict__ Cent,
                float* __restrict__ Xhat)
{
    __shared__ unsigned short Ys[128][40];
    __shared__ unsigned short Ps[64][40];
    __shared__ unsigned short csb[TQ_KC];

    const int tid  = threadIdx.x;
    const int lane = tid & 63;
    const int wv   = tid >> 6;
    const int m0 = blockIdx.y * 128;
    const int n0 = blockIdx.x * 64;
    const int wr = (wv >> 1) * 32;
    const int wc = (wv & 1) * 32;
    const int l15 = lane & 15;
    const int k8  = (lane >> 4) * 8;

    const int srow = tid >> 2;
    const int scol = (tid & 3) * 8;
    const int ssc  = SWZ(srow, scol);
    const int bk = tid >> 4;
    const int bnq = (tid & 15) * 4;

    const float* aP = IdxF + (size_t)(m0 + srow) * TQ_D + scol;
    const float* bP = Pi + (size_t)bk * TQ_D + n0 + bnq;

    if (tid < TQ_KC) csb[tid] = f2bf(Cent[tid]);

    f32x4 acc[2][2];
#pragma unroll
    for (int i = 0; i < 2; ++i)
#pragma unroll
        for (int j = 0; j < 2; ++j)
#pragma unroll
            for (int r = 0; r < 4; ++r) acc[i][j][r] = 0.0f;

    float4 va[2], vb;
#pragma unroll
    for (int q = 0; q < 2; ++q) va[q] = *(const float4*)(aP + 4 * q);
    vb = *(const float4*)(bP);

    __syncthreads();

#pragma unroll
    for (int q = 0; q < 2; ++q) {
        ushort4 w;
        const float* fa = (const float*)&va[q];
        w.x = csb[(int)fa[0] & 15];
        w.y = csb[(int)fa[1] & 15];
        w.z = csb[(int)fa[2] & 15];
        w.w = csb[(int)fa[3] & 15];
        *(ushort4*)&Ys[srow][ssc + 4 * q] = w;
    }
    {
        const float* fb = (const float*)&vb;
        Ps[bnq + 0][SWZ(bnq + 0, bk)] = f2bf(fb[0]);
        Ps[bnq + 1][SWZ(bnq + 1, bk)] = f2bf(fb[1]);
        Ps[bnq + 2][SWZ(bnq + 2, bk)] = f2bf(fb[2]);
        Ps[bnq + 3][SWZ(bnq + 3, bk)] = f2bf(fb[3]);
    }
    __syncthreads();

    for (int kt = 0; kt < 32; ++kt) {
        const bool more = (kt + 1) < 32;
        if (more) {
            const float* ap = aP + (kt + 1) * 32;
            const float* bp = bP + (size_t)(kt + 1) * 32 * TQ_D;
#pragma unroll
            for (int q = 0; q < 2; ++q) va[q] = *(const float4*)(ap + 4 * q);
            vb = *(const float4*)(bp);
        }

        bf16x8 af[2], bfr[2];
#pragma unroll
        for (int i = 0; i < 2; ++i) {
            const int r = wr + i * 16 + l15;
            af[i] = *(const bf16x8*)&Ys[r][SWZ(r, k8)];
        }
#pragma unroll
        for (int j = 0; j < 2; ++j) {
            const int r = wc + j * 16 + l15;
            bfr[j] = *(const bf16x8*)&Ps[r][SWZ(r, k8)];
        }

        __builtin_amdgcn_s_setprio(1);
#pragma unroll
        for (int i = 0; i < 2; ++i)
#pragma unroll
            for (int j = 0; j < 2; ++j)
                acc[i][j] = __builtin_amdgcn_mfma_f32_16x16x32_bf16(
                    af[i], bfr[j], acc[i][j], 0, 0, 0);
        __builtin_amdgcn_s_setprio(0);

        if (more) {
            __syncthreads();
#pragma unroll
            for (int q = 0; q < 2; ++q) {
                ushort4 w;
                const float* fa = (const float*)&va[q];
                w.x = csb[(int)fa[0] & 15];
                w.y = csb[(int)fa[1] & 15];
                w.z = csb[(int)fa[2] & 15];
                w.w = csb[(int)fa[3] & 15];
                *(ushort4*)&Ys[srow][ssc + 4 * q] = w;
            }
            {
                const float* fb = (const float*)&vb;
                Ps[bnq + 0][SWZ(bnq + 0, bk)] = f2bf(fb[0]);
                Ps[bnq + 1][SWZ(bnq + 1, bk)] = f2bf(fb[1]);
                Ps[bnq + 2][SWZ(bnq + 2, bk)] = f2bf(fb[2]);
                Ps[bnq + 3][SWZ(bnq + 3, bk)] = f2bf(fb[3]);
            }
            __syncthreads();
        }
    }

#pragma unroll
    for (int i = 0; i < 2; ++i)
#pragma unroll
        for (int j = 0; j < 2; ++j)
#pragma unroll
            for (int r = 0; r < 4; ++r) {
                const int row = wr + i * 16 + (lane >> 4) * 4 + r;
                const int col = wc + j * 16 + l15;
                Xhat[(size_t)(m0 + row) * TQ_D + n0 + col] = acc[i][j][r];
            }
}

// ---------------------------------------------------------------------------
extern "C" void kernel_launch(void* const* d_in, const int* in_sizes, int n_in,
                              void* d_out, int out_size, void* d_ws, size_t ws_size,
                              hipStream_t stream)
{
    const float* x    = (const float*)d_in[0];   // [N, 1024]
    const float* Pi   = (const float*)d_in[1];   // [1024, 1024]
    const float* cent = (const float*)d_in[2];   // [16]
    float* out = (float*)d_out;

    const int ND = in_sizes[0];      // N * 1024
    const int DD = in_sizes[1];      // 1024 * 1024
    const int N  = ND / TQ_D;        // 4096

    float* xhat = out;               // output 0 (scratch: counter+list pre-K2)
    float* oidx = out + ND;          // output 1: indices as float

    unsigned* counter = (unsigned*)xhat;
    unsigned* list    = (unsigned*)xhat + 16;
    const unsigned cap = (unsigned)(ND - 16);

    hipMemsetAsync(counter, 0, 4, stream);   // zero suspect counter

    dim3 grid1(TQ_D / 64, N / 128);  // (16, 32) = 512 blocks

    // Pass 1: 4-term MFMA rotate+quantize -> indices + suspects.
    tq_rq_mfma<<<grid1, 512, 0, stream>>>(x, Pi, cent, oidx, counter, list, cap);

    // Pass 2: exact recompute of suspects (R9 realization).
    tq_fixup_lds<<<1024, 256, 0, stream>>>(x, Pi, cent, oidx, counter, list, cap);

    // Pass 3: dequant + unrotate.
    const size_t wsNeed = 2ull * DD;          // PhT bf16
    if (ws_size >= wsNeed) {
        unsigned short* PhT = (unsigned short*)d_ws;
        dim3 gridT(TQ_D / 64, TQ_D / 64);
        tq_cvt_transpose<<<gridT, 256, 0, stream>>>(Pi, PhT);
        tq_dq_mfma_t<<<grid1, 512, 0, stream>>>(oidx, PhT, cent, xhat);
    } else {
        tq_dq_mfma<<<grid1, 512, 0, stream>>>(oidx, Pi, cent, xhat);
    }
}

// Round 32
// 99.645 us; speedup vs baseline: 1.0342x; 1.0342x over previous
//
#include <hip/hip_runtime.h>
#include <hip/hip_bf16.h>

#define TQ_D   1024
#define TQ_KC  16
#define MERGE_K 512          // OpenBLAS KC-panel boundary (proven R9)
#define TQ_TOL  1.0e-4f      // ~50 sigma of 4-term MFMA vs serial-f32 error
#define LCAP    1024         // per-block LDS suspect-list capacity

#define SWZ(row, col) ((col) ^ ((((row) >> 3) & 1) << 3))

typedef __attribute__((ext_vector_type(8))) short bf16x8;
typedef __attribute__((ext_vector_type(4))) float f32x4;

__device__ __forceinline__ unsigned short f2bf(float f) {
    union { __hip_bfloat16 h; unsigned short s; } u;
    u.h = __float2bfloat16(f);
    return u.s;
}
__device__ __forceinline__ float bf2f(unsigned short s) {
    union { unsigned int u; float f; } v;
    v.u = (unsigned int)s << 16;
    return v.f;
}

// ---------------------------------------------------------------------------
// Convert + transpose: PhT[n][k] = bf16(Pi[k][n]). 64x64 LDS tiles.
// ---------------------------------------------------------------------------
__global__ __launch_bounds__(256)
void tq_cvt_transpose(const float* __restrict__ Pi,
                      unsigned short* __restrict__ PhT)
{
    __shared__ unsigned short tile[64][68];
    const int tid = threadIdx.x;
    const int k0 = blockIdx.y * 64;
    const int n0 = blockIdx.x * 64;
#pragma unroll
    for (int q = 0; q < 16; ++q) {
        const int idx = q * 256 + tid;
        const int r = idx >> 6, c = idx & 63;
        tile[r][c] = f2bf(Pi[(size_t)(k0 + r) * TQ_D + n0 + c]);
    }
    __syncthreads();
#pragma unroll
    for (int q = 0; q < 16; ++q) {
        const int idx = q * 256 + tid;
        const int r = idx >> 6, c = idx & 63;
        PhT[(size_t)(n0 + r) * TQ_D + k0 + c] = tile[c][r];
    }
}

// ---------------------------------------------------------------------------
// K1-MFMA (4-term, 8-wave, 128x64 — R30 champion): y = x @ Pi^T via bf16
// hi/lo split, f32 MFMA accum, literal f32 argmin; suspects (dist < TOL)
// aggregated per-block in LDS, one global atomicAdd per block.
// ---------------------------------------------------------------------------
__global__ __launch_bounds__(512)
void tq_rq_mfma(const float* __restrict__ X,
                const float* __restrict__ Pi,
                const float* __restrict__ Cent,
                float* __restrict__ OutIdx,
                unsigned* __restrict__ Counter,
                unsigned* __restrict__ List,
                unsigned cap)
{
    __shared__ unsigned short XhS[128][40];
    __shared__ unsigned short XlS[128][40];
    __shared__ unsigned short PhS[64][40];
    __shared__ unsigned short PlS[64][40];
    __shared__ unsigned lcount;
    __shared__ unsigned gbase;
    __shared__ unsigned llist[LCAP];

    const int tid  = threadIdx.x;
    const int lane = tid & 63;
    const int wv   = tid >> 6;
    const int m0 = blockIdx.y * 128;
    const int n0 = blockIdx.x * 64;
    const int wr = (wv >> 1) * 32;
    const int wc = (wv & 1) * 32;
    const int l15 = lane & 15;
    const int k8  = (lane >> 4) * 8;

    const int srow = tid >> 2;
    const int scol = (tid & 3) * 8;
    const int ssc  = SWZ(srow, scol);
    const int brow = tid >> 3;
    const int bcol = (tid & 7) * 4;
    const int bsc  = SWZ(brow, bcol);

    const float* aP = X  + (size_t)(m0 + srow) * TQ_D + scol;
    const float* bP = Pi + (size_t)(n0 + brow) * TQ_D + bcol;

    if (tid == 0) lcount = 0;

    f32x4 acc[2][2];
#pragma unroll
    for (int i = 0; i < 2; ++i)
#pragma unroll
        for (int j = 0; j < 2; ++j)
#pragma unroll
            for (int r = 0; r < 4; ++r) acc[i][j][r] = 0.0f;

    float4 va[2], vb;
#pragma unroll
    for (int q = 0; q < 2; ++q) va[q] = *(const float4*)(aP + 4 * q);
    vb = *(const float4*)(bP);

#pragma unroll
    for (int q = 0; q < 2; ++q) {
        ushort4 ah, al;
        const float* fa = (const float*)&va[q];
        ah.x = f2bf(fa[0]); al.x = f2bf(fa[0] - bf2f(ah.x));
        ah.y = f2bf(fa[1]); al.y = f2bf(fa[1] - bf2f(ah.y));
        ah.z = f2bf(fa[2]); al.z = f2bf(fa[2] - bf2f(ah.z));
        ah.w = f2bf(fa[3]); al.w = f2bf(fa[3] - bf2f(ah.w));
        *(ushort4*)&XhS[srow][ssc + 4 * q] = ah;
        *(ushort4*)&XlS[srow][ssc + 4 * q] = al;
    }
    {
        ushort4 bh, bl;
        const float* fb = (const float*)&vb;
        bh.x = f2bf(fb[0]); bl.x = f2bf(fb[0] - bf2f(bh.x));
        bh.y = f2bf(fb[1]); bl.y = f2bf(fb[1] - bf2f(bh.y));
        bh.z = f2bf(fb[2]); bl.z = f2bf(fb[2] - bf2f(bh.z));
        bh.w = f2bf(fb[3]); bl.w = f2bf(fb[3] - bf2f(bh.w));
        *(ushort4*)&PhS[brow][bsc] = bh;
        *(ushort4*)&PlS[brow][bsc] = bl;
    }
    __syncthreads();

    for (int kt = 0; kt < 32; ++kt) {
        const bool more = (kt + 1) < 32;
        if (more) {
            const float* ap = aP + (kt + 1) * 32;
            const float* bp = bP + (kt + 1) * 32;
#pragma unroll
            for (int q = 0; q < 2; ++q) va[q] = *(const float4*)(ap + 4 * q);
            vb = *(const float4*)(bp);
        }

        bf16x8 afh[2], afl[2], bfh[2], bfl[2];
#pragma unroll
        for (int i = 0; i < 2; ++i) {
            const int r = wr + i * 16 + l15;
            const int kk = SWZ(r, k8);
            afh[i] = *(const bf16x8*)&XhS[r][kk];
            afl[i] = *(const bf16x8*)&XlS[r][kk];
        }
#pragma unroll
        for (int j = 0; j < 2; ++j) {
            const int r = wc + j * 16 + l15;
            const int kk = SWZ(r, k8);
            bfh[j] = *(const bf16x8*)&PhS[r][kk];
            bfl[j] = *(const bf16x8*)&PlS[r][kk];
        }

#pragma unroll
        for (int i = 0; i < 2; ++i)
#pragma unroll
            for (int j = 0; j < 2; ++j) {
                acc[i][j] = __builtin_amdgcn_mfma_f32_16x16x32_bf16(
                    afh[i], bfh[j], acc[i][j], 0, 0, 0);
                acc[i][j] = __builtin_amdgcn_mfma_f32_16x16x32_bf16(
                    afl[i], bfh[j], acc[i][j], 0, 0, 0);
                acc[i][j] = __builtin_amdgcn_mfma_f32_16x16x32_bf16(
                    afh[i], bfl[j], acc[i][j], 0, 0, 0);
                acc[i][j] = __builtin_amdgcn_mfma_f32_16x16x32_bf16(
                    afl[i], bfl[j], acc[i][j], 0, 0, 0);
            }

        if (more) {
            __syncthreads();
#pragma unroll
            for (int q = 0; q < 2; ++q) {
                ushort4 ah, al;
                const float* fa = (const float*)&va[q];
                ah.x = f2bf(fa[0]); al.x = f2bf(fa[0] - bf2f(ah.x));
                ah.y = f2bf(fa[1]); al.y = f2bf(fa[1] - bf2f(ah.y));
                ah.z = f2bf(fa[2]); al.z = f2bf(fa[2] - bf2f(ah.z));
                ah.w = f2bf(fa[3]); al.w = f2bf(fa[3] - bf2f(ah.w));
                *(ushort4*)&XhS[srow][ssc + 4 * q] = ah;
                *(ushort4*)&XlS[srow][ssc + 4 * q] = al;
            }
            {
                ushort4 bh, bl;
                const float* fb = (const float*)&vb;
                bh.x = f2bf(fb[0]); bl.x = f2bf(fb[0] - bf2f(bh.x));
                bh.y = f2bf(fb[1]); bl.y = f2bf(fb[1] - bf2f(bh.y));
                bh.z = f2bf(fb[2]); bl.z = f2bf(fb[2] - bf2f(bh.z));
                bh.w = f2bf(fb[3]); bl.w = f2bf(fb[3] - bf2f(bh.w));
                *(ushort4*)&PhS[brow][bsc] = bh;
                *(ushort4*)&PlS[brow][bsc] = bl;
            }
            __syncthreads();
        }
    }

    float c[TQ_KC];
#pragma unroll
    for (int q = 0; q < TQ_KC; ++q) c[q] = Cent[q];

#pragma unroll
    for (int i = 0; i < 2; ++i)
#pragma unroll
        for (int j = 0; j < 2; ++j)
#pragma unroll
            for (int r = 0; r < 4; ++r) {
                const int row = m0 + wr + i * 16 + (lane >> 4) * 4 + r;
                const int col = n0 + wc + j * 16 + l15;
                const float y = acc[i][j][r];
                int best = 0;
                float bd = fabsf(y - c[0]);
#pragma unroll
                for (int q = 1; q < TQ_KC; ++q) {
                    const float d = fabsf(y - c[q]);
                    if (d < bd) { bd = d; best = q; }
                }
                float dist = 1e30f;
#pragma unroll
                for (int q = 0; q < TQ_KC - 1; ++q) {
                    const float mid = 0.5f * (c[q] + c[q + 1]);
                    dist = fminf(dist, fabsf(y - mid));
                }
                if (dist < TQ_TOL) {
                    const unsigned id = ((unsigned)row << 10) | (unsigned)col;
                    const unsigned ls = atomicAdd(&lcount, 1u);
                    if (ls < LCAP) {
                        llist[ls] = id;
                    } else {
                        const unsigned gs = atomicAdd(Counter, 1u);
                        if (gs < cap) List[gs] = id;
                    }
                }
                OutIdx[(size_t)row * TQ_D + col] = (float)best;
            }

    __syncthreads();
    if (tid == 0) {
        const unsigned cnt = min(lcount, (unsigned)LCAP);
        gbase = (cnt > 0) ? atomicAdd(Counter, cnt) : 0u;
    }
    __syncthreads();
    const unsigned cnt = min(lcount, (unsigned)LCAP);
    for (unsigned s = tid; s < cnt; s += 512) {
        const unsigned g = gbase + s;
        if (g < cap) List[g] = llist[s];
    }
}

// ---------------------------------------------------------------------------
// Fixup (proven R21-R30): 8 suspects/block; exact R9 serial chains from LDS.
// ---------------------------------------------------------------------------
__global__ __launch_bounds__(256)
void tq_fixup_lds(const float* __restrict__ X,
                  const float* __restrict__ Pi,
                  const float* __restrict__ Cent,
                  float* __restrict__ OutIdx,
                  const unsigned* __restrict__ Counter,
                  const unsigned* __restrict__ List,
                  unsigned cap)
{
    __shared__ float Rows[8][2][1024];
    __shared__ float part[8][2];
    __shared__ unsigned ids[8];

    const int tid = threadIdx.x;
    const unsigned count = min(*Counter, cap);

    for (unsigned base = blockIdx.x * 8; base < count; base += gridDim.x * 8) {
        const unsigned nsus = min(8u, count - base);

        if (tid < 8) ids[tid] = (tid < nsus) ? List[base + tid] : 0u;
        __syncthreads();

#pragma unroll
        for (int q = 0; q < 16; ++q) {
            const int lin = q * 256 + tid;
            const int sus = lin >> 9;
            const int rowsel = (lin >> 8) & 1;
            const int f4 = lin & 255;
            if ((unsigned)sus < nsus) {
                const unsigned id = ids[sus];
                const int m = id >> 10;
                const int n = id & (TQ_D - 1);
                const float* src = rowsel ? (Pi + (size_t)n * TQ_D)
                                          : (X + (size_t)m * TQ_D);
                *(float4*)&Rows[sus][rowsel][f4 * 4] =
                    *(const float4*)(src + f4 * 4);
            }
        }
        __syncthreads();

        if (tid < 16 && (unsigned)(tid >> 1) < nsus) {
            const int sus = tid >> 1;
            const int p = tid & 1;
            const int kb = p * MERGE_K;
            float a = 0.0f;
            for (int k = 0; k < MERGE_K; k += 4) {
                const float4 xa = *(const float4*)&Rows[sus][0][kb + k];
                const float4 pa = *(const float4*)&Rows[sus][1][kb + k];
                a = fmaf(xa.x, pa.x, a);
                a = fmaf(xa.y, pa.y, a);
                a = fmaf(xa.z, pa.z, a);
                a = fmaf(xa.w, pa.w, a);
            }
            part[sus][p] = a;
        }
        __syncthreads();

        if (tid < (int)nsus) {
            const float y = part[tid][0] + part[tid][1];
            float c[TQ_KC];
#pragma unroll
            for (int q = 0; q < TQ_KC; ++q) c[q] = Cent[q];
            int best = 0;
            float bd = fabsf(y - c[0]);
#pragma unroll
            for (int q = 1; q < TQ_KC; ++q) {
                const float d = fabsf(y - c[q]);
                if (d < bd) { bd = d; best = q; }
            }
            const unsigned id = ids[tid];
            OutIdx[(size_t)(id >> 10) * TQ_D + (id & (TQ_D - 1))] = (float)best;
        }
        __syncthreads();
    }
}

// ---------------------------------------------------------------------------
// K2-MFMA (8-wave 128x64, PhT input — R30 champion): x_hat = dequant @ Pi.
// B-staging is a vectorized ushort4 row copy from PhT.
// ---------------------------------------------------------------------------
__global__ __launch_bounds__(512)
void tq_dq_mfma_t(const float* __restrict__ IdxF,
                  const unsigned short* __restrict__ PhT,
                  const float* __restrict__ Cent,
                  float* __restrict__ Xhat)
{
    __shared__ unsigned short Ys[128][40];
    __shared__ unsigned short Ps[64][40];
    __shared__ unsigned short csb[TQ_KC];

    const int tid  = threadIdx.x;
    const int lane = tid & 63;
    const int wv   = tid >> 6;
    const int m0 = blockIdx.y * 128;
    const int n0 = blockIdx.x * 64;
    const int wr = (wv >> 1) * 32;
    const int wc = (wv & 1) * 32;
    const int l15 = lane & 15;
    const int k8  = (lane >> 4) * 8;

    const int srow = tid >> 2;
    const int scol = (tid & 3) * 8;
    const int ssc  = SWZ(srow, scol);
    const int brow = tid >> 3;
    const int bcol = (tid & 7) * 4;
    const int bsc  = SWZ(brow, bcol);

    const float* aP = IdxF + (size_t)(m0 + srow) * TQ_D + scol;
    const unsigned short* bP = PhT + (size_t)(n0 + brow) * TQ_D + bcol;

    if (tid < TQ_KC) csb[tid] = f2bf(Cent[tid]);

    f32x4 acc[2][2];
#pragma unroll
    for (int i = 0; i < 2; ++i)
#pragma unroll
        for (int j = 0; j < 2; ++j)
#pragma unroll
            for (int r = 0; r < 4; ++r) acc[i][j][r] = 0.0f;

    float4 va[2];
    ushort4 vb;
#pragma unroll
    for (int q = 0; q < 2; ++q) va[q] = *(const float4*)(aP + 4 * q);
    vb = *(const ushort4*)(bP);

    __syncthreads();   // csb ready

#pragma unroll
    for (int q = 0; q < 2; ++q) {
        ushort4 w;
        const float* fa = (const float*)&va[q];
        w.x = csb[(int)fa[0] & 15];
        w.y = csb[(int)fa[1] & 15];
        w.z = csb[(int)fa[2] & 15];
        w.w = csb[(int)fa[3] & 15];
        *(ushort4*)&Ys[srow][ssc + 4 * q] = w;
    }
    *(ushort4*)&Ps[brow][bsc] = vb;
    __syncthreads();

    for (int kt = 0; kt < 32; ++kt) {
        const bool more = (kt + 1) < 32;
        if (more) {
            const float* ap = aP + (kt + 1) * 32;
#pragma unroll
            for (int q = 0; q < 2; ++q) va[q] = *(const float4*)(ap + 4 * q);
            vb = *(const ushort4*)(bP + (kt + 1) * 32);
        }

        bf16x8 af[2], bfr[2];
#pragma unroll
        for (int i = 0; i < 2; ++i) {
            const int r = wr + i * 16 + l15;
            af[i] = *(const bf16x8*)&Ys[r][SWZ(r, k8)];
        }
#pragma unroll
        for (int j = 0; j < 2; ++j) {
            const int r = wc + j * 16 + l15;
            bfr[j] = *(const bf16x8*)&Ps[r][SWZ(r, k8)];
        }

#pragma unroll
        for (int i = 0; i < 2; ++i)
#pragma unroll
            for (int j = 0; j < 2; ++j)
                acc[i][j] = __builtin_amdgcn_mfma_f32_16x16x32_bf16(
                    af[i], bfr[j], acc[i][j], 0, 0, 0);

        if (more) {
            __syncthreads();
#pragma unroll
            for (int q = 0; q < 2; ++q) {
                ushort4 w;
                const float* fa = (const float*)&va[q];
                w.x = csb[(int)fa[0] & 15];
                w.y = csb[(int)fa[1] & 15];
                w.z = csb[(int)fa[2] & 15];
                w.w = csb[(int)fa[3] & 15];
                *(ushort4*)&Ys[srow][ssc + 4 * q] = w;
            }
            *(ushort4*)&Ps[brow][bsc] = vb;
            __syncthreads();
        }
    }

#pragma unroll
    for (int i = 0; i < 2; ++i)
#pragma unroll
        for (int j = 0; j < 2; ++j)
#pragma unroll
            for (int r = 0; r < 4; ++r) {
                const int row = wr + i * 16 + (lane >> 4) * 4 + r;
                const int col = wc + j * 16 + l15;
                Xhat[(size_t)(m0 + row) * TQ_D + n0 + col] = acc[i][j][r];
            }
}

// ---------------------------------------------------------------------------
// Fallback K2 (proven R29 fused): transposed scalar staging.
// ---------------------------------------------------------------------------
__global__ __launch_bounds__(512)
void tq_dq_mfma(const float* __restrict__ IdxF,
                const float* __restrict__ Pi,
                const float* __restrict__ Cent,
                float* __restrict__ Xhat)
{
    __shared__ unsigned short Ys[128][40];
    __shared__ unsigned short Ps[64][40];
    __shared__ unsigned short csb[TQ_KC];

    const int tid  = threadIdx.x;
    const int lane = tid & 63;
    const int wv   = tid >> 6;
    const int m0 = blockIdx.y * 128;
    const int n0 = blockIdx.x * 64;
    const int wr = (wv >> 1) * 32;
    const int wc = (wv & 1) * 32;
    const int l15 = lane & 15;
    const int k8  = (lane >> 4) * 8;

    const int srow = tid >> 2;
    const int scol = (tid & 3) * 8;
    const int ssc  = SWZ(srow, scol);
    const int bk = tid >> 4;
    const int bnq = (tid & 15) * 4;

    const float* aP = IdxF + (size_t)(m0 + srow) * TQ_D + scol;
    const float* bP = Pi + (size_t)bk * TQ_D + n0 + bnq;

    if (tid < TQ_KC) csb[tid] = f2bf(Cent[tid]);

    f32x4 acc[2][2];
#pragma unroll
    for (int i = 0; i < 2; ++i)
#pragma unroll
        for (int j = 0; j < 2; ++j)
#pragma unroll
            for (int r = 0; r < 4; ++r) acc[i][j][r] = 0.0f;

    float4 va[2], vb;
#pragma unroll
    for (int q = 0; q < 2; ++q) va[q] = *(const float4*)(aP + 4 * q);
    vb = *(const float4*)(bP);

    __syncthreads();

#pragma unroll
    for (int q = 0; q < 2; ++q) {
        ushort4 w;
        const float* fa = (const float*)&va[q];
        w.x = csb[(int)fa[0] & 15];
        w.y = csb[(int)fa[1] & 15];
        w.z = csb[(int)fa[2] & 15];
        w.w = csb[(int)fa[3] & 15];
        *(ushort4*)&Ys[srow][ssc + 4 * q] = w;
    }
    {
        const float* fb = (const float*)&vb;
        Ps[bnq + 0][SWZ(bnq + 0, bk)] = f2bf(fb[0]);
        Ps[bnq + 1][SWZ(bnq + 1, bk)] = f2bf(fb[1]);
        Ps[bnq + 2][SWZ(bnq + 2, bk)] = f2bf(fb[2]);
        Ps[bnq + 3][SWZ(bnq + 3, bk)] = f2bf(fb[3]);
    }
    __syncthreads();

    for (int kt = 0; kt < 32; ++kt) {
        const bool more = (kt + 1) < 32;
        if (more) {
            const float* ap = aP + (kt + 1) * 32;
            const float* bp = bP + (size_t)(kt + 1) * 32 * TQ_D;
#pragma unroll
            for (int q = 0; q < 2; ++q) va[q] = *(const float4*)(ap + 4 * q);
            vb = *(const float4*)(bp);
        }

        bf16x8 af[2], bfr[2];
#pragma unroll
        for (int i = 0; i < 2; ++i) {
            const int r = wr + i * 16 + l15;
            af[i] = *(const bf16x8*)&Ys[r][SWZ(r, k8)];
        }
#pragma unroll
        for (int j = 0; j < 2; ++j) {
            const int r = wc + j * 16 + l15;
            bfr[j] = *(const bf16x8*)&Ps[r][SWZ(r, k8)];
        }

#pragma unroll
        for (int i = 0; i < 2; ++i)
#pragma unroll
            for (int j = 0; j < 2; ++j)
                acc[i][j] = __builtin_amdgcn_mfma_f32_16x16x32_bf16(
                    af[i], bfr[j], acc[i][j], 0, 0, 0);

        if (more) {
            __syncthreads();
#pragma unroll
            for (int q = 0; q < 2; ++q) {
                ushort4 w;
                const float* fa = (const float*)&va[q];
                w.x = csb[(int)fa[0] & 15];
                w.y = csb[(int)fa[1] & 15];
                w.z = csb[(int)fa[2] & 15];
                w.w = csb[(int)fa[3] & 15];
                *(ushort4*)&Ys[srow][ssc + 4 * q] = w;
            }
            {
                const float* fb = (const float*)&vb;
                Ps[bnq + 0][SWZ(bnq + 0, bk)] = f2bf(fb[0]);
                Ps[bnq + 1][SWZ(bnq + 1, bk)] = f2bf(fb[1]);
                Ps[bnq + 2][SWZ(bnq + 2, bk)] = f2bf(fb[2]);
                Ps[bnq + 3][SWZ(bnq + 3, bk)] = f2bf(fb[3]);
            }
            __syncthreads();
        }
    }

#pragma unroll
    for (int i = 0; i < 2; ++i)
#pragma unroll
        for (int j = 0; j < 2; ++j)
#pragma unroll
            for (int r = 0; r < 4; ++r) {
                const int row = wr + i * 16 + (lane >> 4) * 4 + r;
                const int col = wc + j * 16 + l15;
                Xhat[(size_t)(m0 + row) * TQ_D + n0 + col] = acc[i][j][r];
            }
}

// ---------------------------------------------------------------------------
extern "C" void kernel_launch(void* const* d_in, const int* in_sizes, int n_in,
                              void* d_out, int out_size, void* d_ws, size_t ws_size,
                              hipStream_t stream)
{
    const float* x    = (const float*)d_in[0];   // [N, 1024]
    const float* Pi   = (const float*)d_in[1];   // [1024, 1024]
    const float* cent = (const float*)d_in[2];   // [16]
    float* out = (float*)d_out;

    const int ND = in_sizes[0];      // N * 1024
    const int DD = in_sizes[1];      // 1024 * 1024
    const int N  = ND / TQ_D;        // 4096

    float* xhat = out;               // output 0 (scratch: counter+list pre-K2)
    float* oidx = out + ND;          // output 1: indices as float

    unsigned* counter = (unsigned*)xhat;
    unsigned* list    = (unsigned*)xhat + 16;
    const unsigned cap = (unsigned)(ND - 16);

    hipMemsetAsync(counter, 0, 4, stream);   // zero suspect counter

    dim3 grid1(TQ_D / 64, N / 128);  // (16, 32) = 512 blocks

    // Pass 1: 4-term MFMA rotate+quantize -> indices + suspects.
    tq_rq_mfma<<<grid1, 512, 0, stream>>>(x, Pi, cent, oidx, counter, list, cap);

    // Pass 2: exact recompute of suspects (R9 realization).
    tq_fixup_lds<<<1024, 256, 0, stream>>>(x, Pi, cent, oidx, counter, list, cap);

    // Pass 3: dequant + unrotate.
    const size_t wsNeed = 2ull * DD;          // PhT bf16
    if (ws_size >= wsNeed) {
        unsigned short* PhT = (unsigned short*)d_ws;
        dim3 gridT(TQ_D / 64, TQ_D / 64);
        tq_cvt_transpose<<<gridT, 256, 0, stream>>>(Pi, PhT);
        tq_dq_mfma_t<<<grid1, 512, 0, stream>>>(oidx, PhT, cent, xhat);
    } else {
        tq_dq_mfma<<<grid1, 512, 0, stream>>>(oidx, Pi, cent, xhat);
    }
}